// Round 12
// baseline (285.307 us; speedup 1.0000x reference)
//
#include <hip/hip_runtime.h>

typedef _Float16 f16;
typedef f16 f16x4 __attribute__((ext_vector_type(4)));
typedef f16 f16x8 __attribute__((ext_vector_type(8)));
typedef __fp16 h16x2 __attribute__((ext_vector_type(2)));
typedef float floatx4 __attribute__((ext_vector_type(4)));

#define QSCALE 11.5415603271117f  // 8 * log2(e): score computed in log2 domain

// XOR-swizzled LDS tiles, stride 64 f16 (no pad): phys chunk = chunk ^ (row & 7).
// Column-parallel fragment reads (16 lanes x 16 rows, same chunk) spread across
// all 8 bank groups instead of the 8-way conflict a 36-bank row stride causes.

// x fp32 -> fp16, 4 elems/thread
__global__ __launch_bounds__(256) void convert_f32_f16(const float* __restrict__ in,
                                                       f16* __restrict__ out, int n) {
  int i = (blockIdx.x * 256 + threadIdx.x) * 4;
  if (i >= n) return;
  float4 v = *(const float4*)(in + i);
  f16x4 o = {(f16)v.x, (f16)v.y, (f16)v.z, (f16)v.w};
  *(f16x4*)(out + i) = o;
}

// W [K][N] fp32 -> Wt [N][K] fp16, 64x64 tiles via LDS: coalesced both sides
__global__ __launch_bounds__(256) void transpose_f32_f16_tiled(const float* __restrict__ in,
                                                               f16* __restrict__ out,
                                                               int K, int N) {
  __shared__ f16 tile[64][72];
  int k0 = blockIdx.x * 64, n0 = blockIdx.y * 64;
  int tid = threadIdx.x;
  int r = tid >> 4, c4 = (tid & 15) * 4;
  for (int p = 0; p < 4; ++p) {
    int rr = r + p * 16;
    float4 v = *(const float4*)(in + (size_t)(k0 + rr) * N + n0 + c4);
    tile[c4 + 0][rr] = (f16)v.x;
    tile[c4 + 1][rr] = (f16)v.y;
    tile[c4 + 2][rr] = (f16)v.z;
    tile[c4 + 3][rr] = (f16)v.w;
  }
  __syncthreads();
  int rn = tid >> 3, ck = (tid & 7) * 8;
  for (int p = 0; p < 2; ++p) {
    int rr = rn + p * 32;
    *(uint4*)(out + (size_t)(n0 + rr) * K + k0 + ck) = *(const uint4*)(&tile[rr][ck]);
  }
}

// qkv = x16 @ WqkvT^T (fp16 in, fp32 acc). Epilogue scatters per-head:
//   cols [0,768):     q16 [bh][t][64], PRE-SCALED by 8*log2(e)
//   cols [768,1536):  k16 [bh][t][64]
//   cols [1536,2304): vT  [bh][64][2048] (pre-transposed)
__global__ __launch_bounds__(256) void gemm1_qkv(const f16* __restrict__ A,
                                                 const f16* __restrict__ Bt,
                                                 f16* __restrict__ q16, f16* __restrict__ k16,
                                                 f16* __restrict__ vt) {
  __shared__ f16 As[128 * 64];
  __shared__ f16 Bs[128 * 64];
  int tid = threadIdx.x;
  int lane = tid & 63, wid = tid >> 6;
  int quad = lane >> 4, l16 = lane & 15;
  int wy = wid >> 1, wx = wid & 1;
  int m0 = blockIdx.x * 128, n0 = blockIdx.y * 128;
  int srow = tid >> 3;
  int schunk = tid & 7;                       // logical 8-f16 chunk
  int scol = schunk * 8;
  int swz = (schunk ^ (srow & 7)) * 8;        // swizzled f16 offset in row
  floatx4 acc[4][4] = {};
  for (int k0 = 0; k0 < 768; k0 += 64) {
    for (int p = 0; p < 4; ++p) {
      int r = srow + p * 32;
      *(uint4*)(As + r * 64 + swz) = *(const uint4*)(A + (size_t)(m0 + r) * 768 + k0 + scol);
      *(uint4*)(Bs + r * 64 + swz) = *(const uint4*)(Bt + (size_t)(n0 + r) * 768 + k0 + scol);
    }
    __syncthreads();
    for (int kk = 0; kk < 2; ++kk) {
      int cch = kk * 4 + quad;  // logical chunk of the fragment column
      f16x8 af[4], bfr[4];
      for (int i = 0; i < 4; ++i) {
        int row = wy * 64 + i * 16 + l16;
        af[i] = *(const f16x8*)(As + row * 64 + ((cch ^ (l16 & 7)) * 8));
      }
      for (int j = 0; j < 4; ++j) {
        int row = wx * 64 + j * 16 + l16;
        bfr[j] = *(const f16x8*)(Bs + row * 64 + ((cch ^ (l16 & 7)) * 8));
      }
      for (int i = 0; i < 4; ++i)
        for (int j = 0; j < 4; ++j)
          acc[i][j] = __builtin_amdgcn_mfma_f32_16x16x32_f16(af[i], bfr[j], acc[i][j], 0, 0, 0);
    }
    __syncthreads();
  }
  for (int i = 0; i < 4; ++i)
    for (int j = 0; j < 4; ++j)
      for (int r = 0; r < 4; ++r) {
        int row = m0 + wy * 64 + i * 16 + quad * 4 + r;
        int col = n0 + wx * 64 + j * 16 + l16;
        float a = acc[i][j][r];
        int b = row >> 11, t = row & 2047;
        if (col < 768) {
          int h = col >> 6, d = col & 63;
          q16[((size_t)(b * 12 + h)) * 131072 + (size_t)t * 64 + d] = (f16)(a * QSCALE);
        } else if (col < 1536) {
          int c = col - 768;
          int h = c >> 6, d = c & 63;
          k16[((size_t)(b * 12 + h)) * 131072 + (size_t)t * 64 + d] = (f16)a;
        } else {
          int c = col - 1536;
          int h = c >> 6, d = c & 63;
          vt[((size_t)(b * 12 + h)) * 131072 + (size_t)d * 2048 + t] = (f16)a;
        }
      }
}

// C[M,N](fp32) = A[M,K](f16) * Bt[N,K]^T(f16)
__global__ __launch_bounds__(256) void gemm_bt_f16(const f16* __restrict__ A,
                                                   const f16* __restrict__ Bt,
                                                   float* __restrict__ C,
                                                   int M, int N, int K) {
  __shared__ f16 As[128 * 64];
  __shared__ f16 Bs[128 * 64];
  int tid = threadIdx.x;
  int lane = tid & 63, wid = tid >> 6;
  int quad = lane >> 4, l16 = lane & 15;
  int wy = wid >> 1, wx = wid & 1;
  int m0 = blockIdx.x * 128, n0 = blockIdx.y * 128;
  int srow = tid >> 3;
  int schunk = tid & 7;
  int scol = schunk * 8;
  int swz = (schunk ^ (srow & 7)) * 8;
  floatx4 acc[4][4] = {};
  for (int k0 = 0; k0 < K; k0 += 64) {
    for (int p = 0; p < 4; ++p) {
      int r = srow + p * 32;
      *(uint4*)(As + r * 64 + swz) = *(const uint4*)(A + (size_t)(m0 + r) * K + k0 + scol);
      *(uint4*)(Bs + r * 64 + swz) = *(const uint4*)(Bt + (size_t)(n0 + r) * K + k0 + scol);
    }
    __syncthreads();
    for (int kk = 0; kk < 2; ++kk) {
      int cch = kk * 4 + quad;
      f16x8 af[4], bfr[4];
      for (int i = 0; i < 4; ++i) {
        int row = wy * 64 + i * 16 + l16;
        af[i] = *(const f16x8*)(As + row * 64 + ((cch ^ (l16 & 7)) * 8));
      }
      for (int j = 0; j < 4; ++j) {
        int row = wx * 64 + j * 16 + l16;
        bfr[j] = *(const f16x8*)(Bs + row * 64 + ((cch ^ (l16 & 7)) * 8));
      }
      for (int i = 0; i < 4; ++i)
        for (int j = 0; j < 4; ++j)
          acc[i][j] = __builtin_amdgcn_mfma_f32_16x16x32_f16(af[i], bfr[j], acc[i][j], 0, 0, 0);
    }
    __syncthreads();
  }
  for (int i = 0; i < 4; ++i) {
    int row = m0 + wy * 64 + i * 16 + quad * 4;
    for (int j = 0; j < 4; ++j) {
      int col = n0 + wx * 64 + j * 16 + l16;
      for (int r = 0; r < 4; ++r)
        C[(size_t)(row + r) * N + col] = acc[i][j][r];
    }
  }
}

// Flash attention v7: S^T orientation, 128-wide s-tile, XOR-swizzled LDS.
// LDS = Ks[128x64]+Vt[64x128] = 32 KB -> 5 blocks/CU. P exp'd in f16.
__global__ __launch_bounds__(256, 2) void flash_attn(const f16* __restrict__ q16,
                                                     const f16* __restrict__ k16,
                                                     const f16* __restrict__ vT,
                                                     f16* __restrict__ y) {
  __shared__ f16 Ks[128 * 64];   // [s][d], 8-chunk XOR swizzle
  __shared__ f16 Vt[64 * 128];   // [d][s], 16-chunk XOR swizzle
  const int T = 2048;
  // XCD-locality remap: all 32 q-tiles of a head land on one XCD's L2
  int xcd = blockIdx.x & 7, yb = blockIdx.x >> 3;
  int bh = xcd * 6 + (yb >> 5);
  int qt = yb & 31;
  int b = bh / 12, h = bh - b * 12;
  int tid = threadIdx.x;
  int lane = tid & 63, wid = tid >> 6;
  int quad = lane >> 4, l16 = lane & 15;
  int rk = tid >> 3, kch = tid & 7;            // K staging: 32 rows x 8 chunks
  int rv = tid >> 4, vch = tid & 15;           // V staging: 16 rows x 16 chunks
  int kswz = (kch ^ (rk & 7)) * 8;
  int vswz = (vch ^ rv) * 8;
  size_t hb = (size_t)bh * T * 64;

  f16x8 qf[2];  // B-operand: col m = l16 -> Q row (qt*64 + wid*16 + l16)
  {
    size_t qrow = hb + (size_t)(qt * 64 + wid * 16 + l16) * 64 + quad * 8;
    qf[0] = *(const f16x8*)(q16 + qrow);
    qf[1] = *(const f16x8*)(q16 + qrow + 32);
  }
  f16x4 ones4;
  for (int e = 0; e < 4; ++e) ones4[e] = (f16)1.0f;

  float m_i = -1e30f, l_i = 0.f;
  floatx4 o[4] = {};  // O^T: dn = i*16 + quad*4 + reg, m = l16

  for (int kt = 0; kt < 16; ++kt) {
    if (kt) __syncthreads();  // prior iteration's LDS reads complete
    for (int p = 0; p < 4; ++p) {
      int r = rk + p * 32;
      *(uint4*)(Ks + r * 64 + kswz) =
          *(const uint4*)(k16 + hb + (size_t)(kt * 128 + r) * 64 + kch * 8);
      int d = rv + p * 16;
      *(uint4*)(Vt + d * 128 + vswz) =
          *(const uint4*)(vT + hb + (size_t)d * T + kt * 128 + vch * 8);
    }
    __syncthreads();

    // S^T[s][m] = (8*log2e) * k.q : A-frag = K rows (s), B-frag = Q (m)
    floatx4 sf[8];
    const floatx4 z4 = {0.f, 0.f, 0.f, 0.f};
    for (int i = 0; i < 8; ++i) sf[i] = z4;
    for (int kk = 0; kk < 2; ++kk)
      for (int i = 0; i < 8; ++i) {
        int row = i * 16 + l16;
        f16x8 kf = *(const f16x8*)(Ks + row * 64 + (((kk * 4 + quad) ^ (l16 & 7)) * 8));
        sf[i] = __builtin_amdgcn_mfma_f32_16x16x32_f16(kf, qf[kk], sf[i], 0, 0, 0);
      }

    // online softmax over s (base 2): 32 in-lane values + cross-quad butterfly
    float mx = fmaxf(fmaxf(sf[0][0], sf[0][1]), fmaxf(sf[0][2], sf[0][3]));
    for (int i = 1; i < 8; ++i)
      mx = fmaxf(mx, fmaxf(fmaxf(sf[i][0], sf[i][1]), fmaxf(sf[i][2], sf[i][3])));
    mx = fmaxf(mx, __shfl_xor(mx, 16));
    mx = fmaxf(mx, __shfl_xor(mx, 32));
    float m_new = fmaxf(m_i, mx);
    float alpha = exp2f(m_i - m_new);
    m_i = m_new;
    for (int i = 0; i < 4; ++i) o[i] *= alpha;

    // pack u = t - m_new to f16, exp in f16 (P only needs f16 for the PV MFMA)
    f16x4 pf[8];
    for (int i = 0; i < 8; ++i) {
      union { h16x2 h; f16 f[2]; } a2, b2;
      a2.h = __builtin_amdgcn_cvt_pkrtz(sf[i][0] - m_new, sf[i][1] - m_new);
      b2.h = __builtin_amdgcn_cvt_pkrtz(sf[i][2] - m_new, sf[i][3] - m_new);
      f16x4 uu = {a2.f[0], a2.f[1], b2.f[0], b2.f[1]};
#if __has_builtin(__builtin_elementwise_exp2)
      pf[i] = __builtin_elementwise_exp2(uu);
#else
      for (int r = 0; r < 4; ++r) pf[i][r] = (f16)exp2f((float)uu[r]);
#endif
    }

    // row sums via ones-MFMA (every lane gets full sum over s)
    floatx4 rs = z4;
    for (int si = 0; si < 8; ++si)
      rs = __builtin_amdgcn_mfma_f32_16x16x16f16(ones4, pf[si], rs, 0, 0, 0);
    l_i = l_i * alpha + rs[0];

    // O^T += V^T . P^T : A-frag = Vt rows (dn), B-frag = pf
    for (int i = 0; i < 4; ++i)
      for (int si = 0; si < 8; ++si) {
        int d = i * 16 + l16;
        int cch = si * 2 + (quad >> 1);  // logical 8-f16 chunk of col si*16+quad*4
        f16x4 vf = *(const f16x4*)(Vt + d * 128 + ((cch ^ l16) * 8) + (quad & 1) * 4);
        o[i] = __builtin_amdgcn_mfma_f32_16x16x16f16(vf, pf[si], o[i], 0, 0, 0);
      }
  }

  // epilogue: O^T[dn][m] -> y[b, t=qt*64+wid*16+l16, h*64+dn]
  float invl = 1.0f / l_i;
  int t = qt * 64 + wid * 16 + l16;
  size_t off = ((size_t)(b * T + t)) * 768 + h * 64;
  for (int i = 0; i < 4; ++i)
    for (int r = 0; r < 4; ++r)
      y[off + i * 16 + quad * 4 + r] = (f16)(o[i][r] * invl);
}

extern "C" void kernel_launch(void* const* d_in, const int* in_sizes, int n_in,
                              void* d_out, int out_size, void* d_ws, size_t ws_size,
                              hipStream_t stream) {
  const float* x     = (const float*)d_in[0];  // [4,2048,768] fp32
  const float* Wqkv  = (const float*)d_in[1];  // [768,2304] fp32
  const float* Wproj = (const float*)d_in[2];  // [768,768] fp32
  float* out = (float*)d_out;                  // [4,2048,768] fp32
  char* ws = (char*)d_ws;
  f16* x16    = (f16*)ws;                  // 8192*768*2 = 12,582,912 B each
  f16* q16    = (f16*)(ws + 12582912);
  f16* k16    = (f16*)(ws + 25165824);
  f16* vT16   = (f16*)(ws + 37748736);
  f16* y16    = (f16*)(ws + 50331648);
  f16* WqkvT  = (f16*)(ws + 62914560);     // 2304*768*2 = 3,538,944 B
  f16* WprojT = (f16*)(ws + 66453504);     //  768*768*2 = 1,179,648 B
                                           // total 67,633,152 B

  convert_f32_f16<<<6144, 256, 0, stream>>>(x, x16, 6291456);
  transpose_f32_f16_tiled<<<dim3(12, 36), 256, 0, stream>>>(Wqkv, WqkvT, 768, 2304);
  transpose_f32_f16_tiled<<<dim3(12, 12), 256, 0, stream>>>(Wproj, WprojT, 768, 768);
  gemm1_qkv<<<dim3(64, 18), 256, 0, stream>>>(x16, WqkvT, q16, k16, vT16);
  flash_attn<<<1536, 256, 0, stream>>>(q16, k16, vT16, y16);
  gemm_bt_f16<<<dim3(64, 6), 256, 0, stream>>>(y16, WprojT, out, 8192, 768, 768);
}

// Round 13
// 259.389 us; speedup vs baseline: 1.0999x; 1.0999x over previous
//
#include <hip/hip_runtime.h>

typedef _Float16 f16;
typedef f16 f16x4 __attribute__((ext_vector_type(4)));
typedef f16 f16x8 __attribute__((ext_vector_type(8)));
typedef __fp16 h16x2 __attribute__((ext_vector_type(2)));
typedef float floatx4 __attribute__((ext_vector_type(4)));

#define LDT 72  // 64+8 pad f16 stride for GEMM tiles: fragment reads are 2-way (free)
#define QSCALE 11.5415603271117f  // 8 * log2(e): score computed in log2 domain

// W [K][N] fp32 -> Wt [N][K] fp16, 64x64 tiles via LDS: coalesced both sides
__global__ __launch_bounds__(256) void transpose_f32_f16_tiled(const float* __restrict__ in,
                                                               f16* __restrict__ out,
                                                               int K, int N) {
  __shared__ f16 tile[64][LDT];
  int k0 = blockIdx.x * 64, n0 = blockIdx.y * 64;
  int tid = threadIdx.x;
  int r = tid >> 4, c4 = (tid & 15) * 4;
  for (int p = 0; p < 4; ++p) {
    int rr = r + p * 16;
    float4 v = *(const float4*)(in + (size_t)(k0 + rr) * N + n0 + c4);
    tile[c4 + 0][rr] = (f16)v.x;
    tile[c4 + 1][rr] = (f16)v.y;
    tile[c4 + 2][rr] = (f16)v.z;
    tile[c4 + 3][rr] = (f16)v.w;
  }
  __syncthreads();
  int rn = tid >> 3, ck = (tid & 7) * 8;
  for (int p = 0; p < 2; ++p) {
    int rr = rn + p * 32;
    *(uint4*)(out + (size_t)(n0 + rr) * K + k0 + ck) = *(const uint4*)(&tile[rr][ck]);
  }
}

// qkv = x @ WqkvT^T (x fp32 converted during staging, fp32 acc). Epilogue scatters:
//   cols [0,768):     q16 [bh][t][64], PRE-SCALED by 8*log2(e)
//   cols [768,1536):  k16 [bh][t][64]
//   cols [1536,2304): vT  [bh][64][2048] (pre-transposed)
__global__ __launch_bounds__(256) void gemm1_qkv(const float* __restrict__ A,
                                                 const f16* __restrict__ Bt,
                                                 f16* __restrict__ q16, f16* __restrict__ k16,
                                                 f16* __restrict__ vt) {
  __shared__ f16 As[128 * LDT];
  __shared__ f16 Bs[128 * LDT];
  int tid = threadIdx.x;
  int lane = tid & 63, wid = tid >> 6;
  int quad = lane >> 4, l16 = lane & 15;
  int wy = wid >> 1, wx = wid & 1;
  int m0 = blockIdx.x * 128, n0 = blockIdx.y * 128;
  int srow = tid >> 3, scol = (tid & 7) * 8;
  floatx4 acc[4][4] = {};
  for (int k0 = 0; k0 < 768; k0 += 64) {
    for (int p = 0; p < 4; ++p) {
      int r = srow + p * 32;
      const float* src = A + (size_t)(m0 + r) * 768 + k0 + scol;
      float4 v0 = *(const float4*)(src);
      float4 v1 = *(const float4*)(src + 4);
      f16x8 hv = {(f16)v0.x, (f16)v0.y, (f16)v0.z, (f16)v0.w,
                  (f16)v1.x, (f16)v1.y, (f16)v1.z, (f16)v1.w};
      *(f16x8*)(As + r * LDT + scol) = hv;
      *(uint4*)(Bs + r * LDT + scol) = *(const uint4*)(Bt + (size_t)(n0 + r) * 768 + k0 + scol);
    }
    __syncthreads();
    for (int kk = 0; kk < 64; kk += 32) {
      f16x8 af[4], bfr[4];
      for (int i = 0; i < 4; ++i)
        af[i] = *(const f16x8*)(As + (wy * 64 + i * 16 + l16) * LDT + kk + quad * 8);
      for (int j = 0; j < 4; ++j)
        bfr[j] = *(const f16x8*)(Bs + (wx * 64 + j * 16 + l16) * LDT + kk + quad * 8);
      for (int i = 0; i < 4; ++i)
        for (int j = 0; j < 4; ++j)
          acc[i][j] = __builtin_amdgcn_mfma_f32_16x16x32_f16(af[i], bfr[j], acc[i][j], 0, 0, 0);
    }
    __syncthreads();
  }
  for (int i = 0; i < 4; ++i)
    for (int j = 0; j < 4; ++j)
      for (int r = 0; r < 4; ++r) {
        int row = m0 + wy * 64 + i * 16 + quad * 4 + r;
        int col = n0 + wx * 64 + j * 16 + l16;
        float a = acc[i][j][r];
        int b = row >> 11, t = row & 2047;
        if (col < 768) {
          int h = col >> 6, d = col & 63;
          q16[((size_t)(b * 12 + h)) * 131072 + (size_t)t * 64 + d] = (f16)(a * QSCALE);
        } else if (col < 1536) {
          int c = col - 768;
          int h = c >> 6, d = c & 63;
          k16[((size_t)(b * 12 + h)) * 131072 + (size_t)t * 64 + d] = (f16)a;
        } else {
          int c = col - 1536;
          int h = c >> 6, d = c & 63;
          vt[((size_t)(b * 12 + h)) * 131072 + (size_t)d * 2048 + t] = (f16)a;
        }
      }
}

// C[M,N](fp32) = A[M,K](f16) * Bt[N,K]^T(f16)
__global__ __launch_bounds__(256) void gemm_bt_f16(const f16* __restrict__ A,
                                                   const f16* __restrict__ Bt,
                                                   float* __restrict__ C,
                                                   int M, int N, int K) {
  __shared__ f16 As[128 * LDT];
  __shared__ f16 Bs[128 * LDT];
  int tid = threadIdx.x;
  int lane = tid & 63, wid = tid >> 6;
  int quad = lane >> 4, l16 = lane & 15;
  int wy = wid >> 1, wx = wid & 1;
  int m0 = blockIdx.x * 128, n0 = blockIdx.y * 128;
  int srow = tid >> 3, scol = (tid & 7) * 8;
  floatx4 acc[4][4] = {};
  for (int k0 = 0; k0 < K; k0 += 64) {
    for (int p = 0; p < 4; ++p) {
      int r = srow + p * 32;
      *(uint4*)(As + r * LDT + scol) = *(const uint4*)(A + (size_t)(m0 + r) * K + k0 + scol);
      *(uint4*)(Bs + r * LDT + scol) = *(const uint4*)(Bt + (size_t)(n0 + r) * K + k0 + scol);
    }
    __syncthreads();
    for (int kk = 0; kk < 64; kk += 32) {
      f16x8 af[4], bfr[4];
      for (int i = 0; i < 4; ++i)
        af[i] = *(const f16x8*)(As + (wy * 64 + i * 16 + l16) * LDT + kk + quad * 8);
      for (int j = 0; j < 4; ++j)
        bfr[j] = *(const f16x8*)(Bs + (wx * 64 + j * 16 + l16) * LDT + kk + quad * 8);
      for (int i = 0; i < 4; ++i)
        for (int j = 0; j < 4; ++j)
          acc[i][j] = __builtin_amdgcn_mfma_f32_16x16x32_f16(af[i], bfr[j], acc[i][j], 0, 0, 0);
    }
    __syncthreads();
  }
  for (int i = 0; i < 4; ++i) {
    int row = m0 + wy * 64 + i * 16 + quad * 4;
    for (int j = 0; j < 4; ++j) {
      int col = n0 + wx * 64 + j * 16 + l16;
      for (int r = 0; r < 4; ++r)
        C[(size_t)(row + r) * N + col] = acc[i][j][r];
    }
  }
}

// Flash attention v8: S^T orientation, 128-wide s-tile, 512-thread blocks
// (128 q-rows, 8 waves share one K/V stage -> half the staging + barriers/work;
// occupancy wave-limited: 4 blocks x 8 waves = 32 waves/CU potential).
// XOR-swizzled LDS, 32 KB.
__global__ __launch_bounds__(512, 1) void flash_attn(const f16* __restrict__ q16,
                                                     const f16* __restrict__ k16,
                                                     const f16* __restrict__ vT,
                                                     f16* __restrict__ y) {
  __shared__ f16 Ks[128 * 64];   // [s][d], 8-chunk XOR swizzle
  __shared__ f16 Vt[64 * 128];   // [d][s], 16-chunk XOR swizzle
  const int T = 2048;
  // XCD-locality remap: all 16 q-tiles of a head land on one XCD's L2
  int xcd = blockIdx.x & 7, yb = blockIdx.x >> 3;  // yb in [0,96)
  int bh = xcd * 6 + (yb >> 4);
  int qt = yb & 15;
  int b = bh / 12, h = bh - b * 12;
  int tid = threadIdx.x;
  int lane = tid & 63, wid = tid >> 6;             // wid in [0,8)
  int quad = lane >> 4, l16 = lane & 15;
  int rk = tid >> 3, kch = tid & 7;                // K staging: 64 rows x 8 chunks/pass
  int rv = tid >> 4, vch = tid & 15;               // V staging: 32 rows x 16 chunks/pass
  int kswz = (kch ^ (rk & 7)) * 8;
  int vswz = (vch ^ (rv & 15)) * 8;
  size_t hb = (size_t)bh * T * 64;

  f16x8 qf[2];  // B-operand: col m = l16 -> Q row (qt*128 + wid*16 + l16)
  {
    size_t qrow = hb + (size_t)(qt * 128 + wid * 16 + l16) * 64 + quad * 8;
    qf[0] = *(const f16x8*)(q16 + qrow);
    qf[1] = *(const f16x8*)(q16 + qrow + 32);
  }
  f16x4 ones4;
  for (int e = 0; e < 4; ++e) ones4[e] = (f16)1.0f;

  float m_i = -1e30f, l_i = 0.f;
  floatx4 o[4] = {};  // O^T: dn = i*16 + quad*4 + reg, m = l16

  for (int kt = 0; kt < 16; ++kt) {
    if (kt) __syncthreads();  // prior iteration's LDS reads complete
    for (int p = 0; p < 2; ++p) {
      int r = rk + p * 64;
      *(uint4*)(Ks + r * 64 + kswz) =
          *(const uint4*)(k16 + hb + (size_t)(kt * 128 + r) * 64 + kch * 8);
      int d = rv + p * 32;
      *(uint4*)(Vt + d * 128 + vswz) =
          *(const uint4*)(vT + hb + (size_t)d * T + kt * 128 + vch * 8);
    }
    __syncthreads();

    // S^T[s][m] = (8*log2e) * k.q : A-frag = K rows (s), B-frag = Q (m)
    floatx4 sf[8];
    const floatx4 z4 = {0.f, 0.f, 0.f, 0.f};
    for (int i = 0; i < 8; ++i) sf[i] = z4;
    for (int kk = 0; kk < 2; ++kk)
      for (int i = 0; i < 8; ++i) {
        int row = i * 16 + l16;
        f16x8 kf = *(const f16x8*)(Ks + row * 64 + (((kk * 4 + quad) ^ (l16 & 7)) * 8));
        sf[i] = __builtin_amdgcn_mfma_f32_16x16x32_f16(kf, qf[kk], sf[i], 0, 0, 0);
      }

    // online softmax over s (base 2): 32 in-lane values + cross-quad butterfly
    float mx = fmaxf(fmaxf(sf[0][0], sf[0][1]), fmaxf(sf[0][2], sf[0][3]));
    for (int i = 1; i < 8; ++i)
      mx = fmaxf(mx, fmaxf(fmaxf(sf[i][0], sf[i][1]), fmaxf(sf[i][2], sf[i][3])));
    mx = fmaxf(mx, __shfl_xor(mx, 16));
    mx = fmaxf(mx, __shfl_xor(mx, 32));
    float m_new = fmaxf(m_i, mx);
    float alpha = exp2f(m_i - m_new);
    m_i = m_new;
    for (int i = 0; i < 4; ++i) o[i] *= alpha;

    // pack u = t - m_new to f16, exp in f16 (P only needs f16 for the PV MFMA)
    f16x4 pf[8];
    for (int i = 0; i < 8; ++i) {
      union { h16x2 h; f16 f[2]; } a2, b2;
      a2.h = __builtin_amdgcn_cvt_pkrtz(sf[i][0] - m_new, sf[i][1] - m_new);
      b2.h = __builtin_amdgcn_cvt_pkrtz(sf[i][2] - m_new, sf[i][3] - m_new);
      f16x4 uu = {a2.f[0], a2.f[1], b2.f[0], b2.f[1]};
#if __has_builtin(__builtin_elementwise_exp2)
      pf[i] = __builtin_elementwise_exp2(uu);
#else
      for (int r = 0; r < 4; ++r) pf[i][r] = (f16)exp2f((float)uu[r]);
#endif
    }

    // row sums via ones-MFMA (every lane gets full sum over s)
    floatx4 rs = z4;
    for (int si = 0; si < 8; ++si)
      rs = __builtin_amdgcn_mfma_f32_16x16x16f16(ones4, pf[si], rs, 0, 0, 0);
    l_i = l_i * alpha + rs[0];

    // O^T += V^T . P^T : A-frag = Vt rows (dn), B-frag = pf
    for (int i = 0; i < 4; ++i)
      for (int si = 0; si < 8; ++si) {
        int d = i * 16 + l16;
        int cch = si * 2 + (quad >> 1);  // logical 8-f16 chunk of col si*16+quad*4
        f16x4 vf = *(const f16x4*)(Vt + d * 128 + ((cch ^ l16) * 8) + (quad & 1) * 4);
        o[i] = __builtin_amdgcn_mfma_f32_16x16x16f16(vf, pf[si], o[i], 0, 0, 0);
      }
  }

  // epilogue: O^T[dn][m] -> y[b, t=qt*128+wid*16+l16, h*64+dn]
  float invl = 1.0f / l_i;
  int t = qt * 128 + wid * 16 + l16;
  size_t off = ((size_t)(b * T + t)) * 768 + h * 64;
  for (int i = 0; i < 4; ++i)
    for (int r = 0; r < 4; ++r)
      y[off + i * 16 + quad * 4 + r] = (f16)(o[i][r] * invl);
}

extern "C" void kernel_launch(void* const* d_in, const int* in_sizes, int n_in,
                              void* d_out, int out_size, void* d_ws, size_t ws_size,
                              hipStream_t stream) {
  const float* x     = (const float*)d_in[0];  // [4,2048,768] fp32
  const float* Wqkv  = (const float*)d_in[1];  // [768,2304] fp32
  const float* Wproj = (const float*)d_in[2];  // [768,768] fp32
  float* out = (float*)d_out;                  // [4,2048,768] fp32
  char* ws = (char*)d_ws;
  f16* q16    = (f16*)ws;                  // 8192*768*2 = 12,582,912 B each
  f16* k16    = (f16*)(ws + 12582912);
  f16* vT16   = (f16*)(ws + 25165824);
  f16* y16    = (f16*)(ws + 37748736);
  f16* WqkvT  = (f16*)(ws + 50331648);     // 2304*768*2 = 3,538,944 B
  f16* WprojT = (f16*)(ws + 53870592);     //  768*768*2 = 1,179,648 B
                                           // total 55,050,240 B

  transpose_f32_f16_tiled<<<dim3(12, 36), 256, 0, stream>>>(Wqkv, WqkvT, 768, 2304);
  transpose_f32_f16_tiled<<<dim3(12, 12), 256, 0, stream>>>(Wproj, WprojT, 768, 768);
  gemm1_qkv<<<dim3(64, 18), 256, 0, stream>>>(x, WqkvT, q16, k16, vT16);
  flash_attn<<<768, 512, 0, stream>>>(q16, k16, vT16, y16);
  gemm_bt_f16<<<dim3(64, 6), 256, 0, stream>>>(y16, WprojT, out, 8192, 768, 768);
}